// Round 3
// baseline (316.869 us; speedup 1.0000x reference)
//
#include <hip/hip_runtime.h>
#include <cstdint>
#include <cstddef>

// ---------- types ----------
typedef __bf16 bf16_t;
typedef __bf16 bf16x8 __attribute__((ext_vector_type(8)));
typedef __bf16 bf16x4 __attribute__((ext_vector_type(4)));
typedef float f32x4 __attribute__((ext_vector_type(4)));

// async global->LDS, 16B per lane. LDS dest must be wave-uniform base + lane*16.
#define GL2LDS16(gptr, lptr)                                                   \
  __builtin_amdgcn_global_load_lds(                                            \
      (__attribute__((address_space(1))) void*)(gptr),                         \
      (__attribute__((address_space(3))) void*)(lptr), 16, 0, 0)

// fast 2^x (hardware transcendental; inputs bounded here)
__device__ __forceinline__ float fast_exp2(float x) {
  float r;
  asm volatile("v_exp_f32 %0, %1" : "=v"(r) : "v"(x));
  return r;
}

// ---------- problem constants ----------
#define BATCH 2
#define T_SEQ 2048
#define NH 16
#define NKV 4
#define HD 128
#define EMB 2048
#define KVDIM (NKV * HD)       // 512
#define MROWS (BATCH * T_SEQ)  // 4096

// =====================================================================
// fused fp32 -> bf16 conversion for all 5 inputs (one dispatch)
// =====================================================================
__global__ void cvt_all(const float4* __restrict__ x,  const float4* __restrict__ wq,
                        const float4* __restrict__ wk, const float4* __restrict__ wv,
                        const float4* __restrict__ wo,
                        bf16x4* __restrict__ xb,  bf16x4* __restrict__ wqb,
                        bf16x4* __restrict__ wkb, bf16x4* __restrict__ wvb,
                        bf16x4* __restrict__ wob) {
  const int blk = blockIdx.x;
  const float4* src;
  bf16x4* dst;
  int base;
  if (blk < 8192)       { src = x;  dst = xb;  base = blk; }
  else if (blk < 12288) { src = wq; dst = wqb; base = blk - 8192; }
  else if (blk < 13312) { src = wk; dst = wkb; base = blk - 12288; }
  else if (blk < 14336) { src = wv; dst = wvb; base = blk - 13312; }
  else                  { src = wo; dst = wob; base = blk - 14336; }
  const int i = base * 256 + threadIdx.x;
  const float4 v = src[i];
  dst[i] = bf16x4{(__bf16)v.x, (__bf16)v.y, (__bf16)v.z, (__bf16)v.w};
}

// =====================================================================
// Fused QKV GEMM — 256x256, 4-phase PIPELINED schedule.
// 8 waves (512 thr), wave tile 128x64, BK=64, LDS 128 KiB, 16B-block XOR
// swizzle (blk ^= row&7), ONE barrier per phase, counted vmcnt(2) at
// ph4-start, setprio(1) around MFMA clusters.
//
// Pipelining: every ds_read issues in a section whose MFMA cluster does
// NOT consume it (overlap LDS port with MFMA pipe):
//   ph1: stage (t+1).A1 -> nxt; read b23   ; MFMA(a03, b01)
//   ph2:                        read a47   ; MFMA(a03, b23)
//   ph3: stage (t+2).B0 -> cur;            ; MFMA(a47, b23)
//   ph4: vmcnt(2) [t+1 landed]; stage (t+2).A0,(t+2).B1 -> cur;
//        read next a03 -> al, next b01 -> (dead b23 set); MFMA(a47, b01)
// Register roles rotate: b-set X/Y alternate b01/b23 each tile; a03/a47
// reload into dead sets. Frag VGPRs unchanged (96) -> 2 waves/SIMD kept.
//
// Hazard check (1 barrier/phase): each stage's target region's readers
// are lgkm-drained before the preceding MFMA cluster, and >=1 barrier
// separates that drain from the stage issue. vmcnt ledger: 6 outstanding
// entering ph1; ph4's vmcnt(2) retires exactly tile t+1's 8 loads.
// N tiles: [0,8) Q | [8,10) K | [10,12) V^T.  Grid: 192 blocks, XCD-swizzled.
// =====================================================================
#define BK8 64
#define NT8 (EMB / BK8)  // 32

__global__ __launch_bounds__(512, 2)
void gemm_qkv8(const bf16_t* __restrict__ A,
               const bf16_t* __restrict__ Wq, const bf16_t* __restrict__ Wk,
               const bf16_t* __restrict__ Wv,
               bf16_t* __restrict__ Qb, bf16_t* __restrict__ Kb,
               bf16_t* __restrict__ Vt, float qalpha)
{
  // rows 0..255: A tile (two 128-row halves), rows 256..511: B tile.
  __shared__ bf16_t lds[2][512 * 64];

  const int tid  = threadIdx.x;
  const int lane = tid & 63;
  const int wv   = tid >> 6;
  const int l15  = lane & 15;
  const int lq   = lane >> 4;

  // XCD-aware bijective swizzle: 192 blocks = 8 XCDs x 24.
  const int bid0 = blockIdx.x;
  const int bid  = (bid0 & 7) * 24 + (bid0 >> 3);
  const int mt = bid / 12, nt = bid % 12;
  const int m0 = mt * 256;

  const bf16_t* Bmat; int ncol0, seg;
  if (nt < 8)       { Bmat = Wq; ncol0 = nt * 256;        seg = 0; }
  else if (nt < 10) { Bmat = Wk; ncol0 = (nt - 8) * 256;  seg = 1; }
  else              { Bmat = Wv; ncol0 = (nt - 10) * 256; seg = 2; }

  const int wm = (wv >> 2) * 128;  // wave M offset (0/128)
  const int wn = (wv & 3) * 64;    // wave N offset (0/64/128/192)

  f32x4 acc[8][4] = {};

  // stage half-tile h of K-tile tsrc into lds[dbuf].
  // h=0: A rows 0-127, h=1: A rows 128-255, h=2: B rows 0-127, h=3: B rows 128-255.
  auto stage = [&](int dbuf, int tsrc, int h) {
    const int k0 = tsrc * BK8;
    const bf16_t* src = (h < 2) ? A : Bmat;
    const int rbase = (h < 2) ? (m0 + h * 128) : (ncol0 + (h - 2) * 128);
    bf16_t* dst = &lds[dbuf][h * 8192];
#pragma unroll
    for (int r = 0; r < 2; ++r) {
      const int c = r * 512 + tid;          // 0..1023, 16B granules
      const int row = c >> 3, p = c & 7;
      const int sb = p ^ (row & 7);
      GL2LDS16(src + (size_t)(rbase + row) * EMB + k0 + sb * 8, dst + c * 8);
    }
  };

  // fragment loads (swizzled reads)
  auto ldA = [&](int buf, int half, bf16x8 (&dst)[4][2]) {
#pragma unroll
    for (int i = 0; i < 4; ++i) {
      const int row = wm + half * 64 + i * 16 + l15;
#pragma unroll
      for (int ks = 0; ks < 2; ++ks)
        dst[i][ks] = *(const bf16x8*)&lds[buf][row * 64 + (((ks * 4 + lq) ^ (row & 7)) * 8)];
    }
  };
  auto ldB = [&](int buf, int half, bf16x8 (&dst)[2][2]) {
#pragma unroll
    for (int j = 0; j < 2; ++j) {
      const int row = 256 + wn + half * 32 + j * 16 + l15;
#pragma unroll
      for (int ks = 0; ks < 2; ++ks)
        dst[j][ks] = *(const bf16x8*)&lds[buf][row * 64 + (((ks * 4 + lq) ^ (row & 7)) * 8)];
    }
  };
  auto mm = [&](bf16x8 (&Af)[4][2], bf16x8 (&Bf)[2][2], int ai, int bj) {
    __builtin_amdgcn_s_setprio(1);
#pragma unroll
    for (int ks = 0; ks < 2; ++ks)
#pragma unroll
      for (int i = 0; i < 4; ++i)
#pragma unroll
        for (int j = 0; j < 2; ++j)
          acc[ai + i][bj + j] = __builtin_amdgcn_mfma_f32_16x16x32_bf16(
              Af[i][ks], Bf[j][ks], acc[ai + i][bj + j], 0, 0, 0);
    __builtin_amdgcn_s_setprio(0);
  };

  // ---- prologue: tile0 complete + tile1 {B0,A0,B1} in flight ----
  stage(0, 0, 0); stage(0, 0, 1); stage(0, 0, 2); stage(0, 0, 3);
  stage(1, 1, 2); stage(1, 1, 0); stage(1, 1, 3);
  asm volatile("s_waitcnt vmcnt(6)" ::: "memory");  // tile0's 8 loads landed
  __builtin_amdgcn_s_barrier();

  bf16x8 al[4][2], ah[4][2], bX[2][2], bY[2][2];
  ldA(0, 0, al);   // tile0 a03
  ldB(0, 0, bX);   // tile0 b01

  // body: tile t in buf cur; b01 = this tile's B-low set, b23 = B-high set
  // (also receives NEXT tile's b01 in ph4 -> role swap each tile).
  auto body = [&](int cur, int t, bf16x8 (&b01)[2][2], bf16x8 (&b23)[2][2]) {
    const int nxt = cur ^ 1;
    const int tn1 = (t + 1 < NT8) ? t + 1 : NT8 - 1;  // clamp src only
    const int tn2 = (t + 2 < NT8) ? t + 2 : NT8 - 1;

    // ---- ph1: stage (t+1).A1 ; prefetch b23 ; MFMA(a03, b01) ----
    stage(nxt, tn1, 1);
    ldB(cur, 1, b23);
    mm(al, b01, 0, 0);
    __builtin_amdgcn_s_barrier();

    // ---- ph2: prefetch a47 ; MFMA(a03, b23) ----
    ldA(cur, 1, ah);
    mm(al, b23, 0, 2);
    __builtin_amdgcn_s_barrier();

    // ---- ph3: stage (t+2).B0 ; MFMA(a47, b23) ----
    stage(cur, tn2, 2);
    mm(ah, b23, 4, 2);
    __builtin_amdgcn_s_barrier();

    // ---- ph4: retire tile t+1 ; stage (t+2).A0/B1 ;
    //           prefetch next a03 -> al, next b01 -> b23 ; MFMA(a47, b01) --
    asm volatile("s_waitcnt vmcnt(2)" ::: "memory");
    stage(cur, tn2, 0);
    stage(cur, tn2, 3);
    ldA(nxt, 0, al);
    ldB(nxt, 0, b23);
    mm(ah, b01, 4, 0);
    __builtin_amdgcn_s_barrier();
  };

#pragma unroll 1
  for (int tt = 0; tt < NT8; tt += 2) {
    body(0, tt,     bX, bY);
    body(1, tt + 1, bY, bX);
  }
  asm volatile("s_waitcnt vmcnt(0)" ::: "memory");  // drain tail dummies

  // ---- epilogue ----
  if (seg == 0) {          // Q: scale + row-major (4096,2048)
#pragma unroll
    for (int i = 0; i < 8; ++i) {
      const int rbase = m0 + wm + i * 16 + lq * 4;
#pragma unroll
      for (int j = 0; j < 4; ++j) {
        const int col = ncol0 + wn + j * 16 + l15;
#pragma unroll
        for (int r = 0; r < 4; ++r)
          Qb[(size_t)(rbase + r) * EMB + col] = (bf16_t)(acc[i][j][r] * qalpha);
      }
    }
  } else if (seg == 1) {   // K: row-major (4096,512)
#pragma unroll
    for (int i = 0; i < 8; ++i) {
      const int rbase = m0 + wm + i * 16 + lq * 4;
#pragma unroll
      for (int j = 0; j < 4; ++j) {
        const int col = ncol0 + wn + j * 16 + l15;
#pragma unroll
        for (int r = 0; r < 4; ++r)
          Kb[(size_t)(rbase + r) * KVDIM + col] = (bf16_t)acc[i][j][r];
      }
    }
  } else {                 // V: transposed, 4 consecutive t per lane
    const int bb = m0 >> 11;
    const int mloc0 = (m0 & 2047) + wm + lq * 4;
#pragma unroll
    for (int i = 0; i < 8; ++i) {
      const int mloc = mloc0 + i * 16;
#pragma unroll
      for (int j = 0; j < 4; ++j) {
        const int d = ncol0 + wn + j * 16 + l15;
        *(bf16x4*)(Vt + (size_t)(bb * KVDIM + d) * T_SEQ + mloc) =
            bf16x4{(__bf16)acc[i][j][0], (__bf16)acc[i][j][1],
                   (__bf16)acc[i][j][2], (__bf16)acc[i][j][3]};
      }
    }
  }
}

// =====================================================================
// GEMM (out-projection): fp32 out.  (m97 structure — port next round)
// =====================================================================
__global__ __launch_bounds__(256, 2)
void gemm_out(const bf16_t* __restrict__ A, const bf16_t* __restrict__ Bm,
              float* __restrict__ C, int M, int N, int K)
{
  __shared__ bf16_t As[128 * 64];
  __shared__ bf16_t Bs[128 * 64];

  const int tid  = threadIdx.x;
  const int lane = tid & 63;
  const int wv   = tid >> 6;
  const int m0 = blockIdx.y * 128;
  const int n0 = blockIdx.x * 128;
  const int wm = (wv >> 1) * 64;
  const int wn = (wv & 1) * 64;
  const int l15 = lane & 15;
  const int lq  = lane >> 4;

  f32x4 acc[4][4] = {};
  const int srow = tid >> 3;
  const int scol = (tid & 7) * 8;

  for (int k0 = 0; k0 < K; k0 += 64) {
#pragma unroll
    for (int r = 0; r < 4; ++r) {
      const int row = r * 32 + srow;
      GL2LDS16(A + (size_t)(m0 + row) * K + k0 + scol, As + row * 64 + scol);
    }
#pragma unroll
    for (int r = 0; r < 4; ++r) {
      const int row = r * 32 + srow;
      GL2LDS16(Bm + (size_t)(n0 + row) * K + k0 + scol, Bs + row * 64 + scol);
    }
    __syncthreads();

#pragma unroll
    for (int ks = 0; ks < 2; ++ks) {
      const int kc = ks * 32 + lq * 8;
      bf16x8 af[4], bf[4];
#pragma unroll
      for (int i = 0; i < 4; ++i)
        af[i] = *(const bf16x8*)(As + (wm + i * 16 + l15) * 64 + kc);
#pragma unroll
      for (int j = 0; j < 4; ++j)
        bf[j] = *(const bf16x8*)(Bs + (wn + j * 16 + l15) * 64 + kc);
#pragma unroll
      for (int i = 0; i < 4; ++i)
#pragma unroll
        for (int j = 0; j < 4; ++j)
          acc[i][j] = __builtin_amdgcn_mfma_f32_16x16x32_bf16(af[i], bf[j], acc[i][j], 0, 0, 0);
    }
    __syncthreads();
  }

#pragma unroll
  for (int i = 0; i < 4; ++i) {
    const int rbase = m0 + wm + i * 16 + lq * 4;
#pragma unroll
    for (int j = 0; j < 4; ++j) {
      const int col = n0 + wn + j * 16 + l15;
#pragma unroll
      for (int r = 0; r < 4; ++r)
        C[(size_t)(rbase + r) * N + col] = acc[i][j][r];
    }
  }
}

// =====================================================================
// Flash attention (R4-verified structure: 65.7 µs, MfmaUtil 21.5%).
// Causal, GQA, no-max exp2 softmax, S^T orientation, P via per-wave LDS,
// x32 PV. q-tile 64 (16 rows/wave); kv tile 64; K/V double-buffered.
// Grid (16,NH,B): block x does qt=31-x then qt=x (33 iters, balanced).
// =====================================================================
#define PSTR 72   // row stride (elements); 144 B = 16B-aligned

__global__ __launch_bounds__(256, 2)
void attn_fwd(const bf16_t* __restrict__ Q, const bf16_t* __restrict__ Kg,
              const bf16_t* __restrict__ Vt, bf16_t* __restrict__ Y)
{
  __shared__ bf16_t Ks[2][64 * 128];   // [t 0..63][16B blk], blk = pos ^ (t&7)
  __shared__ bf16_t Vs[2][128 * 64];   // [d 0..127][16B blk], blk = pos ^ (d&7)
  __shared__ bf16_t Ps[4][16 * PSTR];  // per-wave P[q 0..15][kv 0..63]

  const int tid  = threadIdx.x;
  const int lane = tid & 63;
  const int wv   = tid >> 6;
  const int l15  = lane & 15;
  const int lq   = lane >> 4;
  const int h  = blockIdx.y;
  const int b  = blockIdx.z;
  const int hkv = h >> 2;
  bf16_t* Psw = Ps[wv];

  auto stage = [&](int kt, int bufsel) {
    const int base_t = b * T_SEQ + kt * 64;
#pragma unroll
    for (int r = 0; r < 4; ++r) {
      const int c = r * 256 + tid;
      const int row = c >> 4, p = c & 15;
      const int sb = p ^ (row & 7);
      GL2LDS16(Kg + (size_t)(base_t + row) * KVDIM + hkv * HD + sb * 8,
               &Ks[bufsel][c * 8]);
    }
#pragma unroll
    for (int r = 0; r < 4; ++r) {
      const int c = r * 256 + tid;
      const int row = c >> 3, p = c & 7;
      const int sb = p ^ (row & 7);
      GL2LDS16(Vt + (size_t)(b * KVDIM + hkv * HD + row) * T_SEQ + kt * 64 + sb * 8,
               &Vs[bufsel][c * 8]);
    }
  };

#pragma unroll 1
  for (int ph = 0; ph < 2; ++ph) {
    const int qt = ph ? blockIdx.x : (31 - blockIdx.x);
    const int q0 = qt * 64;
    const int nkt = qt + 1;
    const int qabs = q0 + wv * 16 + l15;   // this lane's q row

    // Q fragments (B-operand: n=l15=q, k=lq*8+j). Q pre-scaled.
    bf16x8 qf[4];
    {
      const bf16_t* qp = Q + ((size_t)(b * T_SEQ + qabs) * NH + h) * HD + lq * 8;
#pragma unroll
      for (int ds = 0; ds < 4; ++ds)
        qf[ds] = *(const bf16x8*)(qp + ds * 32);
    }

    float l_part = 0.f;
    f32x4 o[8];
#pragma unroll
    for (int nb = 0; nb < 8; ++nb) o[nb] = f32x4{0.f, 0.f, 0.f, 0.f};

    __syncthreads();            // prior phase done reading buffers
    stage(0, 0);

    for (int kt = 0; kt < nkt; ++kt) {
      const int cur = kt & 1;
      __syncthreads();          // stage(kt) complete
      if (kt + 1 < nkt) stage(kt + 1, cur ^ 1);

      // ---- S^T = K Q^T : D[kv][q], lane: q=l15, kv=nb*16+lq*4+r ----
      f32x4 s[4];
#pragma unroll
      for (int nb = 0; nb < 4; ++nb) {
        s[nb] = f32x4{0.f, 0.f, 0.f, 0.f};
        const int row = nb * 16 + l15;
        const int r7  = row & 7;
#pragma unroll
        for (int ds = 0; ds < 4; ++ds) {
          const bf16x8 kf = *(const bf16x8*)&Ks[cur][row * 128 + (((ds * 4 + lq) ^ r7) * 8)];
          s[nb] = __builtin_amdgcn_mfma_f32_16x16x32_bf16(kf, qf[ds], s[nb], 0, 0, 0);
        }
      }

      // ---- p = exp2(s) raw (no max), mask only on diagonal tile ----
      const bool dia = (kt == nkt - 1);
#pragma unroll
      for (int nb = 0; nb < 4; ++nb) {
        const int kvb = kt * 64 + nb * 16 + lq * 4;
        float p0, p1, p2, p3;
        if (dia) {
          p0 = (kvb + 0 <= qabs) ? fast_exp2(s[nb][0]) : 0.f;
          p1 = (kvb + 1 <= qabs) ? fast_exp2(s[nb][1]) : 0.f;
          p2 = (kvb + 2 <= qabs) ? fast_exp2(s[nb][2]) : 0.f;
          p3 = (kvb + 3 <= qabs) ? fast_exp2(s[nb][3]) : 0.f;
        } else {
          p0 = fast_exp2(s[nb][0]);
          p1 = fast_exp2(s[nb][1]);
          p2 = fast_exp2(s[nb][2]);
          p3 = fast_exp2(s[nb][3]);
        }
        l_part += (p0 + p1) + (p2 + p3);
        *(bf16x4*)(Psw + l15 * PSTR + nb * 16 + lq * 4) =
            bf16x4{(__bf16)p0, (__bf16)p1, (__bf16)p2, (__bf16)p3};
      }

      // wait ONLY LDS (keep K/V prefetch in flight)
      asm volatile("s_waitcnt lgkmcnt(0)" ::: "memory");

      // ---- O^T += V^T P^T : D[d][q], lane: q=l15, d=nb*16+lq*4+r ----
#pragma unroll
      for (int ks = 0; ks < 2; ++ks) {
        const bf16x8 pf = *(const bf16x8*)(Psw + l15 * PSTR + ks * 32 + lq * 8);
#pragma unroll
        for (int nb = 0; nb < 8; ++nb) {
          const int row = nb * 16 + l15;
          const bf16x8 vf = *(const bf16x8*)&Vs[cur][row * 64 + (((ks * 4 + lq) ^ (row & 7)) * 8)];
          o[nb] = __builtin_amdgcn_mfma_f32_16x16x32_bf16(vf, pf, o[nb], 0, 0, 0);
        }
      }
    }

    // ---- epilogue: reduce l over lq-group (lanes l15+16*lq), store ----
    float lt = l_part;
    lt += __shfl_xor(lt, 16);
    lt += __shfl_xor(lt, 32);
    const float inv = 1.f / lt;
    bf16_t* yp = Y + ((size_t)(b * T_SEQ + qabs) * NH + h) * HD + lq * 4;
#pragma unroll
    for (int nb = 0; nb < 8; ++nb) {
      *(bf16x4*)(yp + nb * 16) = bf16x4{(__bf16)(o[nb][0] * inv), (__bf16)(o[nb][1] * inv),
                                        (__bf16)(o[nb][2] * inv), (__bf16)(o[nb][3] * inv)};
    }
  }
}

// =====================================================================
// launch
// =====================================================================
extern "C" void kernel_launch(void* const* d_in, const int* in_sizes, int n_in,
                              void* d_out, int out_size, void* d_ws, size_t ws_size,
                              hipStream_t stream) {
  const float* x  = (const float*)d_in[0];
  const float* wq = (const float*)d_in[1];
  const float* wk = (const float*)d_in[2];
  const float* wv = (const float*)d_in[3];
  const float* wo = (const float*)d_in[4];
  float* out = (float*)d_out;

  const size_t n_x  = (size_t)MROWS * EMB;
  const size_t n_wq = (size_t)EMB * EMB;
  const size_t n_wk = (size_t)KVDIM * EMB;

  bf16_t* xb  = (bf16_t*)d_ws;
  bf16_t* wqb = xb  + n_x;
  bf16_t* wkb = wqb + n_wq;
  bf16_t* wvb = wkb + n_wk;
  bf16_t* wob = wvb + n_wk;
  bf16_t* Qb  = wob + n_wq;                  // 4096*2048
  bf16_t* Kb  = Qb + (size_t)MROWS * EMB;    // 4096*512
  bf16_t* Vtb = Kb + (size_t)MROWS * KVDIM;  // (B*512)*2048 transposed V
  bf16_t* Yb  = Vtb + (size_t)MROWS * KVDIM; // 4096*2048

  dim3 blk(256);

  cvt_all<<<dim3(18432), blk, 0, stream>>>(
      (const float4*)x, (const float4*)wq, (const float4*)wk, (const float4*)wv, (const float4*)wo,
      (bf16x4*)xb, (bf16x4*)wqb, (bf16x4*)wkb, (bf16x4*)wvb, (bf16x4*)wob);

  const float qalpha = 0.08838834764831845f * 1.4426950408889634f;
  gemm_qkv8<<<dim3(192), dim3(512), 0, stream>>>(xb, wqb, wkb, wvb,
                                                 Qb, Kb, Vtb, qalpha);

  attn_fwd<<<dim3(16, NH, BATCH), blk, 0, stream>>>(Qb, Kb, Vtb, Yb);

  gemm_out<<<dim3(EMB / 128, MROWS / 128), blk, 0, stream>>>(Yb, wob, out, MROWS, EMB, EMB);
}

// Round 4
// 282.444 us; speedup vs baseline: 1.1219x; 1.1219x over previous
//
#include <hip/hip_runtime.h>
#include <cstdint>
#include <cstddef>

// ---------- types ----------
typedef __bf16 bf16_t;
typedef __bf16 bf16x8 __attribute__((ext_vector_type(8)));
typedef __bf16 bf16x4 __attribute__((ext_vector_type(4)));
typedef float f32x4 __attribute__((ext_vector_type(4)));

// async global->LDS, 16B per lane. LDS dest must be wave-uniform base + lane*16.
#define GL2LDS16(gptr, lptr)                                                   \
  __builtin_amdgcn_global_load_lds(                                            \
      (__attribute__((address_space(1))) void*)(gptr),                         \
      (__attribute__((address_space(3))) void*)(lptr), 16, 0, 0)

// fast 2^x (hardware transcendental; inputs bounded here)
__device__ __forceinline__ float fast_exp2(float x) {
  float r;
  asm volatile("v_exp_f32 %0, %1" : "=v"(r) : "v"(x));
  return r;
}

// ---------- problem constants ----------
#define BATCH 2
#define T_SEQ 2048
#define NH 16
#define NKV 4
#define HD 128
#define EMB 2048
#define KVDIM (NKV * HD)       // 512
#define MROWS (BATCH * T_SEQ)  // 4096

// =====================================================================
// fused fp32 -> bf16 conversion for all 5 inputs (one dispatch)
// =====================================================================
__global__ void cvt_all(const float4* __restrict__ x,  const float4* __restrict__ wq,
                        const float4* __restrict__ wk, const float4* __restrict__ wv,
                        const float4* __restrict__ wo,
                        bf16x4* __restrict__ xb,  bf16x4* __restrict__ wqb,
                        bf16x4* __restrict__ wkb, bf16x4* __restrict__ wvb,
                        bf16x4* __restrict__ wob) {
  const int blk = blockIdx.x;
  const float4* src;
  bf16x4* dst;
  int base;
  if (blk < 8192)       { src = x;  dst = xb;  base = blk; }
  else if (blk < 12288) { src = wq; dst = wqb; base = blk - 8192; }
  else if (blk < 13312) { src = wk; dst = wkb; base = blk - 12288; }
  else if (blk < 14336) { src = wv; dst = wvb; base = blk - 13312; }
  else                  { src = wo; dst = wob; base = blk - 14336; }
  const int i = base * 256 + threadIdx.x;
  const float4 v = src[i];
  dst[i] = bf16x4{(__bf16)v.x, (__bf16)v.y, (__bf16)v.z, (__bf16)v.w};
}

// =====================================================================
// Fused QKV GEMM — 256x256, 4-phase pipelined, SINGLE-SET fragments.
// 8 waves (512 thr), wave tile 128x64, BK=64, LDS 128 KiB, 16B-block XOR
// swizzle (blk ^= row&7), 4 barriers/K-tile, counted lgkm waits via
// one-phase-early ds_reads, vmcnt(0) (2-phase-old loads) before ph3.
//
// Quadrants: ph1 MFMA(a03,b01) | ph2 MFMA(a03,b23) | ph3 MFMA(a47,b01)
//            | ph4 MFMA(a47,b23).
// Reads (all single-buffered, reload exactly when dead):
//   ph1: b23(cur)   [dead after ph4? no: used ph2+ph4 -> wait: b23 used
//        ph2 and ph4; reloaded next ph1 -> single set OK]
//   ph2: a47(cur)   [used ph3,ph4; reloaded next ph2]
//   ph3: a03(nxt)   [a03 used ph1,ph2; dead by ph3]
//   ph4: b01(nxt)   [b01 used ph1,ph3; dead by ph4]
// Staging: ALL 4 half-tiles of (t+2) issue at ph4 into cur — every cur
// LDS read has drained by ph3's MFMA (b23@ph2, a47@ph3, a03/b01@ph1),
// and the ph3-end barrier separates. RAW: (t+2) first read @ph3(t+1),
// guarded by ph2(t+1)'s vmcnt(0) (drains exactly those 8 loads).
// Consuming lgkm waits are counted: ph1 lgkm(4), ph2 lgkm(8), ph3
// lgkm(8), ph4 lgkm(0->regs) — compiler-inserted, never a full drain
// before overlap-eligible MFMAs.
// N tiles: [0,8) Q | [8,10) K | [10,12) V^T.  Grid: 192 blocks, XCD-swizzled.
// =====================================================================
#define BK8 64
#define NT8 (EMB / BK8)  // 32

// fragment load macros — plain arrays, constant indices only (no lambdas
// with array refs: that spilled in R3).
#define LDA(dst, buf, half)                                                    \
  _Pragma("unroll")                                                            \
  for (int i_ = 0; i_ < 4; ++i_) {                                             \
    const int row_ = wm + (half) * 64 + i_ * 16 + l15;                         \
    _Pragma("unroll")                                                          \
    for (int ks_ = 0; ks_ < 2; ++ks_)                                          \
      dst[i_][ks_] = *(const bf16x8*)&(buf)[row_ * 64 +                        \
                                            (((ks_ * 4 + lq) ^ (row_ & 7)) * 8)]; \
  }

#define LDB(dst, buf, qoff)                                                    \
  _Pragma("unroll")                                                            \
  for (int j_ = 0; j_ < 2; ++j_) {                                             \
    const int row_ = 256 + wn + (qoff) + j_ * 16 + l15;                        \
    _Pragma("unroll")                                                          \
    for (int ks_ = 0; ks_ < 2; ++ks_)                                          \
      dst[j_][ks_] = *(const bf16x8*)&(buf)[row_ * 64 +                        \
                                            (((ks_ * 4 + lq) ^ (row_ & 7)) * 8)]; \
  }

#define MM(Af, Bf, ai, bj)                                                     \
  __builtin_amdgcn_s_setprio(1);                                               \
  _Pragma("unroll")                                                            \
  for (int ks_ = 0; ks_ < 2; ++ks_)                                            \
    _Pragma("unroll")                                                          \
    for (int i_ = 0; i_ < 4; ++i_)                                             \
      _Pragma("unroll")                                                        \
      for (int j_ = 0; j_ < 2; ++j_)                                           \
        acc[(ai) + i_][(bj) + j_] = __builtin_amdgcn_mfma_f32_16x16x32_bf16(   \
            Af[i_][ks_], Bf[j_][ks_], acc[(ai) + i_][(bj) + j_], 0, 0, 0);     \
  __builtin_amdgcn_s_setprio(0);

__global__ __launch_bounds__(512, 2)
void gemm_qkv8(const bf16_t* __restrict__ A,
               const bf16_t* __restrict__ Wq, const bf16_t* __restrict__ Wk,
               const bf16_t* __restrict__ Wv,
               bf16_t* __restrict__ Qb, bf16_t* __restrict__ Kb,
               bf16_t* __restrict__ Vt, float qalpha)
{
  // rows 0..255: A tile (two 128-row halves), rows 256..511: B tile.
  __shared__ bf16_t lds0[512 * 64];
  __shared__ bf16_t lds1[512 * 64];

  const int tid  = threadIdx.x;
  const int lane = tid & 63;
  const int wv   = tid >> 6;
  const int l15  = lane & 15;
  const int lq   = lane >> 4;

  // XCD-aware bijective swizzle: 192 blocks = 8 XCDs x 24.
  const int bid0 = blockIdx.x;
  const int bid  = (bid0 & 7) * 24 + (bid0 >> 3);
  const int mt = bid / 12, nt = bid % 12;
  const int m0 = mt * 256;

  const bf16_t* Bmat; int ncol0, seg;
  if (nt < 8)       { Bmat = Wq; ncol0 = nt * 256;        seg = 0; }
  else if (nt < 10) { Bmat = Wk; ncol0 = (nt - 8) * 256;  seg = 1; }
  else              { Bmat = Wv; ncol0 = (nt - 10) * 256; seg = 2; }

  const int wm = (wv >> 2) * 128;  // wave M offset (0/128)
  const int wn = (wv & 3) * 64;    // wave N offset (0/64/128/192)

  f32x4 acc[8][4] = {};

  // stage ALL 4 half-tiles of K-tile tsrc into dstbuf (8 gl2lds).
  // Linear LDS dest + inverse-swizzled global source; reads apply
  // blk ^= (row&7) -> 2-way max bank aliasing (free).
  auto stageAll = [&](bf16_t* dstbuf, int tsrc) {
    const int k0 = tsrc * BK8;
#pragma unroll
    for (int h = 0; h < 4; ++h) {
      const bf16_t* src = (h < 2) ? A : Bmat;
      const int rbase = (h < 2) ? (m0 + h * 128) : (ncol0 + (h - 2) * 128);
      bf16_t* dst = dstbuf + h * 8192;
#pragma unroll
      for (int r = 0; r < 2; ++r) {
        const int c = r * 512 + tid;          // 16B granules
        const int row = c >> 3, p = c & 7;
        const int sb = p ^ (row & 7);
        GL2LDS16(src + (size_t)(rbase + row) * EMB + k0 + sb * 8, dst + c * 8);
      }
    }
  };

  // ---- prologue: tile0 + tile1 staged; tile0 landed; preload frags ----
  stageAll(lds0, 0);
  stageAll(lds1, 1);
  asm volatile("s_waitcnt vmcnt(8)" ::: "memory");  // tile0's 8 landed
  __builtin_amdgcn_s_barrier();

  bf16x8 a03[4][2], a47[4][2], b01[2][2], b23[2][2];
  LDA(a03, lds0, 0);
  LDB(b01, lds0, 0);

#pragma unroll 1
  for (int t = 0; t < NT8; ++t) {
    bf16_t* curb = (t & 1) ? lds1 : lds0;
    bf16_t* nxtb = (t & 1) ? lds0 : lds1;
    const int tn2 = (t + 2 < NT8) ? t + 2 : NT8 - 1;  // clamp src; dest
                                                      // parity unchanged

    // -- ph1: read b23(cur) [for ph2]; MFMA(a03,b01) --
    LDB(b23, curb, 32);
    MM(a03, b01, 0, 0);
    __builtin_amdgcn_s_barrier();

    // -- ph2: read a47(cur) [for ph3]; MFMA(a03,b23);
    //    vmcnt(0): tile t+1 (staged ph4(t-1), 2+ phases old) landed.
    //    The "memory" clobber also pins ph3's nxt-buffer reads below. --
    LDA(a47, curb, 1);
    MM(a03, b23, 0, 2);
    asm volatile("s_waitcnt vmcnt(0)" ::: "memory");
    __builtin_amdgcn_s_barrier();

    // -- ph3: read a03(nxt) = tile t+1 [for next ph1]; MFMA(a47,b01) --
    LDA(a03, nxtb, 0);
    MM(a47, b01, 4, 0);
    __builtin_amdgcn_s_barrier();

    // -- ph4: stage tile t+2 into cur (all cur reads drained by ph3);
    //    read b01(nxt) [for next ph1]; MFMA(a47,b23) --
    stageAll(curb, tn2);
    LDB(b01, nxtb, 0);
    MM(a47, b23, 4, 2);
    __builtin_amdgcn_s_barrier();
  }
  asm volatile("s_waitcnt vmcnt(0)" ::: "memory");  // drain tail dummies

  // ---- epilogue ----
  if (seg == 0) {          // Q: scale + row-major (4096,2048)
#pragma unroll
    for (int i = 0; i < 8; ++i) {
      const int rbase = m0 + wm + i * 16 + lq * 4;
#pragma unroll
      for (int j = 0; j < 4; ++j) {
        const int col = ncol0 + wn + j * 16 + l15;
#pragma unroll
        for (int r = 0; r < 4; ++r)
          Qb[(size_t)(rbase + r) * EMB + col] = (bf16_t)(acc[i][j][r] * qalpha);
      }
    }
  } else if (seg == 1) {   // K: row-major (4096,512)
#pragma unroll
    for (int i = 0; i < 8; ++i) {
      const int rbase = m0 + wm + i * 16 + lq * 4;
#pragma unroll
      for (int j = 0; j < 4; ++j) {
        const int col = ncol0 + wn + j * 16 + l15;
#pragma unroll
        for (int r = 0; r < 4; ++r)
          Kb[(size_t)(rbase + r) * KVDIM + col] = (bf16_t)acc[i][j][r];
      }
    }
  } else {                 // V: transposed, 4 consecutive t per lane
    const int bb = m0 >> 11;
    const int mloc0 = (m0 & 2047) + wm + lq * 4;
#pragma unroll
    for (int i = 0; i < 8; ++i) {
      const int mloc = mloc0 + i * 16;
#pragma unroll
      for (int j = 0; j < 4; ++j) {
        const int d = ncol0 + wn + j * 16 + l15;
        *(bf16x4*)(Vt + (size_t)(bb * KVDIM + d) * T_SEQ + mloc) =
            bf16x4{(__bf16)acc[i][j][0], (__bf16)acc[i][j][1],
                   (__bf16)acc[i][j][2], (__bf16)acc[i][j][3]};
      }
    }
  }
}

// =====================================================================
// GEMM (out-projection): fp32 out.
// =====================================================================
__global__ __launch_bounds__(256, 2)
void gemm_out(const bf16_t* __restrict__ A, const bf16_t* __restrict__ Bm,
              float* __restrict__ C, int M, int N, int K)
{
  __shared__ bf16_t As[128 * 64];
  __shared__ bf16_t Bs[128 * 64];

  const int tid  = threadIdx.x;
  const int lane = tid & 63;
  const int wv   = tid >> 6;
  const int m0 = blockIdx.y * 128;
  const int n0 = blockIdx.x * 128;
  const int wm = (wv >> 1) * 64;
  const int wn = (wv & 1) * 64;
  const int l15 = lane & 15;
  const int lq  = lane >> 4;

  f32x4 acc[4][4] = {};
  const int srow = tid >> 3;
  const int scol = (tid & 7) * 8;

  for (int k0 = 0; k0 < K; k0 += 64) {
#pragma unroll
    for (int r = 0; r < 4; ++r) {
      const int row = r * 32 + srow;
      GL2LDS16(A + (size_t)(m0 + row) * K + k0 + scol, As + row * 64 + scol);
    }
#pragma unroll
    for (int r = 0; r < 4; ++r) {
      const int row = r * 32 + srow;
      GL2LDS16(Bm + (size_t)(n0 + row) * K + k0 + scol, Bs + row * 64 + scol);
    }
    __syncthreads();

#pragma unroll
    for (int ks = 0; ks < 2; ++ks) {
      const int kc = ks * 32 + lq * 8;
      bf16x8 af[4], bf[4];
#pragma unroll
      for (int i = 0; i < 4; ++i)
        af[i] = *(const bf16x8*)(As + (wm + i * 16 + l15) * 64 + kc);
#pragma unroll
      for (int j = 0; j < 4; ++j)
        bf[j] = *(const bf16x8*)(Bs + (wn + j * 16 + l15) * 64 + kc);
#pragma unroll
      for (int i = 0; i < 4; ++i)
#pragma unroll
        for (int j = 0; j < 4; ++j)
          acc[i][j] = __builtin_amdgcn_mfma_f32_16x16x32_bf16(af[i], bf[j], acc[i][j], 0, 0, 0);
    }
    __syncthreads();
  }

#pragma unroll
  for (int i = 0; i < 4; ++i) {
    const int rbase = m0 + wm + i * 16 + lq * 4;
#pragma unroll
    for (int j = 0; j < 4; ++j) {
      const int col = n0 + wn + j * 16 + l15;
#pragma unroll
      for (int r = 0; r < 4; ++r)
        C[(size_t)(rbase + r) * N + col] = acc[i][j][r];
    }
  }
}

// =====================================================================
// Flash attention (R4-verified structure: 65.7 µs, MfmaUtil 21.5%).
// Causal, GQA, no-max exp2 softmax, S^T orientation, P via per-wave LDS,
// x32 PV. q-tile 64 (16 rows/wave); kv tile 64; K/V double-buffered.
// Grid (16,NH,B): block x does qt=31-x then qt=x (33 iters, balanced).
// =====================================================================
#define PSTR 72   // row stride (elements); 144 B = 16B-aligned

__global__ __launch_bounds__(256, 2)
void attn_fwd(const bf16_t* __restrict__ Q, const bf16_t* __restrict__ Kg,
              const bf16_t* __restrict__ Vt, bf16_t* __restrict__ Y)
{
  __shared__ bf16_t Ks[2][64 * 128];   // [t 0..63][16B blk], blk = pos ^ (t&7)
  __shared__ bf16_t Vs[2][128 * 64];   // [d 0..127][16B blk], blk = pos ^ (d&7)
  __shared__ bf16_t Ps[4][16 * PSTR];  // per-wave P[q 0..15][kv 0..63]

  const int tid  = threadIdx.x;
  const int lane = tid & 63;
  const int wv   = tid >> 6;
  const int l15  = lane & 15;
  const int lq   = lane >> 4;
  const int h  = blockIdx.y;
  const int b  = blockIdx.z;
  const int hkv = h >> 2;
  bf16_t* Psw = Ps[wv];

  auto stage = [&](int kt, int bufsel) {
    const int base_t = b * T_SEQ + kt * 64;
#pragma unroll
    for (int r = 0; r < 4; ++r) {
      const int c = r * 256 + tid;
      const int row = c >> 4, p = c & 15;
      const int sb = p ^ (row & 7);
      GL2LDS16(Kg + (size_t)(base_t + row) * KVDIM + hkv * HD + sb * 8,
               &Ks[bufsel][c * 8]);
    }
#pragma unroll
    for (int r = 0; r < 4; ++r) {
      const int c = r * 256 + tid;
      const int row = c >> 3, p = c & 7;
      const int sb = p ^ (row & 7);
      GL2LDS16(Vt + (size_t)(b * KVDIM + hkv * HD + row) * T_SEQ + kt * 64 + sb * 8,
               &Vs[bufsel][c * 8]);
    }
  };

#pragma unroll 1
  for (int ph = 0; ph < 2; ++ph) {
    const int qt = ph ? blockIdx.x : (31 - blockIdx.x);
    const int q0 = qt * 64;
    const int nkt = qt + 1;
    const int qabs = q0 + wv * 16 + l15;   // this lane's q row

    // Q fragments (B-operand: n=l15=q, k=lq*8+j). Q pre-scaled.
    bf16x8 qf[4];
    {
      const bf16_t* qp = Q + ((size_t)(b * T_SEQ + qabs) * NH + h) * HD + lq * 8;
#pragma unroll
      for (int ds = 0; ds < 4; ++ds)
        qf[ds] = *(const bf16x8*)(qp + ds * 32);
    }

    float l_part = 0.f;
    f32x4 o[8];
#pragma unroll
    for (int nb = 0; nb < 8; ++nb) o[nb] = f32x4{0.f, 0.f, 0.f, 0.f};

    __syncthreads();            // prior phase done reading buffers
    stage(0, 0);

    for (int kt = 0; kt < nkt; ++kt) {
      const int cur = kt & 1;
      __syncthreads();          // stage(kt) complete
      if (kt + 1 < nkt) stage(kt + 1, cur ^ 1);

      // ---- S^T = K Q^T : D[kv][q], lane: q=l15, kv=nb*16+lq*4+r ----
      f32x4 s[4];
#pragma unroll
      for (int nb = 0; nb < 4; ++nb) {
        s[nb] = f32x4{0.f, 0.f, 0.f, 0.f};
        const int row = nb * 16 + l15;
        const int r7  = row & 7;
#pragma unroll
        for (int ds = 0; ds < 4; ++ds) {
          const bf16x8 kf = *(const bf16x8*)&Ks[cur][row * 128 + (((ds * 4 + lq) ^ r7) * 8)];
          s[nb] = __builtin_amdgcn_mfma_f32_16x16x32_bf16(kf, qf[ds], s[nb], 0, 0, 0);
        }
      }

      // ---- p = exp2(s) raw (no max), mask only on diagonal tile ----
      const bool dia = (kt == nkt - 1);
#pragma unroll
      for (int nb = 0; nb < 4; ++nb) {
        const int kvb = kt * 64 + nb * 16 + lq * 4;
        float p0, p1, p2, p3;
        if (dia) {
          p0 = (kvb + 0 <= qabs) ? fast_exp2(s[nb][0]) : 0.f;
          p1 = (kvb + 1 <= qabs) ? fast_exp2(s[nb][1]) : 0.f;
          p2 = (kvb + 2 <= qabs) ? fast_exp2(s[nb][2]) : 0.f;
          p3 = (kvb + 3 <= qabs) ? fast_exp2(s[nb][3]) : 0.f;
        } else {
          p0 = fast_exp2(s[nb][0]);
          p1 = fast_exp2(s[nb][1]);
          p2 = fast_exp2(s[nb][2]);
          p3 = fast_exp2(s[nb][3]);
        }
        l_part += (p0 + p1) + (p2 + p3);
        *(bf16x4*)(Psw + l15 * PSTR + nb * 16 + lq * 4) =
            bf16x4{(__bf16)p0, (__bf16)p1, (__bf16)p2, (__bf16)p3};
      }

      // wait ONLY LDS (keep K/V prefetch in flight)
      asm volatile("s_waitcnt lgkmcnt(0)" ::: "memory");

      // ---- O^T += V^T P^T : D[d][q], lane: q=l15, d=nb*16+lq*4+r ----
#pragma unroll
      for (int ks = 0; ks < 2; ++ks) {
        const bf16x8 pf = *(const bf16x8*)(Psw + l15 * PSTR + ks * 32 + lq * 8);
#pragma unroll
        for (int nb = 0; nb < 8; ++nb) {
          const int row = nb * 16 + l15;
          const bf16x8 vf = *(const bf16x8*)&Vs[cur][row * 64 + (((ks * 4 + lq) ^ (row & 7)) * 8)];
          o[nb] = __builtin_amdgcn_mfma_f32_16x16x32_bf16(vf, pf, o[nb], 0, 0, 0);
        }
      }
    }

    // ---- epilogue: reduce l over lq-group (lanes l15+16*lq), store ----
    float lt = l_part;
    lt += __shfl_xor(lt, 16);
    lt += __shfl_xor(lt, 32);
    const float inv = 1.f / lt;
    bf16_t* yp = Y + ((size_t)(b * T_SEQ + qabs) * NH + h) * HD + lq * 4;
#pragma unroll
    for (int nb = 0; nb < 8; ++nb) {
      *(bf16x4*)(yp + nb * 16) = bf16x4{(__bf16)(o[nb][0] * inv), (__bf16)(o[nb][1] * inv),
                                        (__bf16)(o[nb][2] * inv), (__bf16)(o[nb][3] * inv)};
    }
  }
}

// =====================================================================
// launch
// =====================================================================
extern "C" void kernel_launch(void* const* d_in, const int* in_sizes, int n_in,
                              void* d_out, int out_size, void* d_ws, size_t ws_size,
                              hipStream_t stream) {
  const float* x  = (const float*)d_in[0];
  const float* wq = (const float*)d_in[1];
  const float* wk = (const float*)d_in[2];
  const float* wv = (const float*)d_in[3];
  const float* wo = (const float*)d_in[4];
  float* out = (float*)d_out;

  const size_t n_x  = (size_t)MROWS * EMB;
  const size_t n_wq = (size_t)EMB * EMB;
  const size_t n_wk = (size_t)KVDIM * EMB;

  bf16_t* xb  = (bf16_t*)d_ws;
  bf16_t* wqb = xb  + n_x;
  bf16_t* wkb = wqb + n_wq;
  bf16_t* wvb = wkb + n_wk;
  bf16_t* wob = wvb + n_wk;
  bf16_t* Qb  = wob + n_wq;                  // 4096*2048
  bf16_t* Kb  = Qb + (size_t)MROWS * EMB;    // 4096*512
  bf16_t* Vtb = Kb + (size_t)MROWS * KVDIM;  // (B*512)*2048 transposed V
  bf16_t* Yb  = Vtb + (size_t)MROWS * KVDIM; // 4096*2048

  dim3 blk(256);

  cvt_all<<<dim3(18432), blk, 0, stream>>>(
      (const float4*)x, (const float4*)wq, (const float4*)wk, (const float4*)wv, (const float4*)wo,
      (bf16x4*)xb, (bf16x4*)wqb, (bf16x4*)wkb, (bf16x4*)wvb, (bf16x4*)wob);

  const float qalpha = 0.08838834764831845f * 1.4426950408889634f;
  gemm_qkv8<<<dim3(192), dim3(512), 0, stream>>>(xb, wqb, wkb, wvb,
                                                 Qb, Kb, Vtb, qalpha);

  attn_fwd<<<dim3(16, NH, BATCH), blk, 0, stream>>>(Qb, Kb, Vtb, Yb);

  gemm_out<<<dim3(EMB / 128, MROWS / 128), blk, 0, stream>>>(Yb, wob, out, MROWS, EMB, EMB);
}

// Round 5
// 273.557 us; speedup vs baseline: 1.1583x; 1.0325x over previous
//
#include <hip/hip_runtime.h>
#include <cstdint>
#include <cstddef>

// ---------- types ----------
typedef __bf16 bf16_t;
typedef __bf16 bf16x8 __attribute__((ext_vector_type(8)));
typedef __bf16 bf16x4 __attribute__((ext_vector_type(4)));
typedef float f32x4 __attribute__((ext_vector_type(4)));

// async global->LDS, 16B per lane. LDS dest must be wave-uniform base + lane*16.
#define GL2LDS16(gptr, lptr)                                                   \
  __builtin_amdgcn_global_load_lds(                                            \
      (__attribute__((address_space(1))) void*)(gptr),                         \
      (__attribute__((address_space(3))) void*)(lptr), 16, 0, 0)

// fast 2^x (hardware transcendental; inputs bounded here)
__device__ __forceinline__ float fast_exp2(float x) {
  float r;
  asm volatile("v_exp_f32 %0, %1" : "=v"(r) : "v"(x));
  return r;
}

// ---------- problem constants ----------
#define BATCH 2
#define T_SEQ 2048
#define NH 16
#define NKV 4
#define HD 128
#define EMB 2048
#define KVDIM (NKV * HD)       // 512
#define MROWS (BATCH * T_SEQ)  // 4096

// =====================================================================
// fused fp32 -> bf16 conversion for all 5 inputs (one dispatch)
// =====================================================================
__global__ void cvt_all(const float4* __restrict__ x,  const float4* __restrict__ wq,
                        const float4* __restrict__ wk, const float4* __restrict__ wv,
                        const float4* __restrict__ wo,
                        bf16x4* __restrict__ xb,  bf16x4* __restrict__ wqb,
                        bf16x4* __restrict__ wkb, bf16x4* __restrict__ wvb,
                        bf16x4* __restrict__ wob) {
  const int blk = blockIdx.x;
  const float4* src;
  bf16x4* dst;
  int base;
  if (blk < 8192)       { src = x;  dst = xb;  base = blk; }
  else if (blk < 12288) { src = wq; dst = wqb; base = blk - 8192; }
  else if (blk < 13312) { src = wk; dst = wkb; base = blk - 12288; }
  else if (blk < 14336) { src = wv; dst = wvb; base = blk - 13312; }
  else                  { src = wo; dst = wob; base = blk - 14336; }
  const int i = base * 256 + threadIdx.x;
  const float4 v = src[i];
  dst[i] = bf16x4{(__bf16)v.x, (__bf16)v.y, (__bf16)v.z, (__bf16)v.w};
}

// =====================================================================
// Fused QKV GEMM — 256x192 tile, 4-phase R2-style schedule, FULL 256-CU
// grid (16 M x 16 N = 256 blocks, 1/CU).
//
// The N-dim 3072 = 16 x 192; tiles straddle Q/K and K/V boundaries.
// Staging selects the source weight matrix PER ROW (per-lane global addr);
// epilogue selects destination PER 16-col FRAGMENT (boundaries 2048/2560
// are 16-multiples -> fragments never straddle).
//
// 8 waves (512 thr), wave tile 128x48 (2M x 4N wave grid), BK=64,
// LDS 112 KiB = 2 x (256 A-rows + 192 B-rows) x 64 x 2B,
// 16B-block XOR swizzle (blk ^= row&7) on both sides, 2 barriers/phase,
// setprio(1) around MFMA, one counted vmcnt(5) per K-tile.
//
// Phases: ph1 MFMA(a03,b01) | ph2 MFMA(a03,b2) | ph3 MFMA(a47,b2)
//         | ph4 MFMA(a47,b01).
// Liveness: B region fully read after ph2 -> stage (t+2).B @ph3[cur];
//           A region fully read after ph3 -> stage (t+2).A0 @ph4[cur];
//           (t+1).A1 @ph1[nxt] (its region last read ph3(t-1)).
// vmcnt ledger (7 loads/tile: A0=2,A1=2,B=3): end-of-tile vmcnt(5)
// retires all of t+1, keeps (t+2).{B,A0} in flight. Prologue: t0 full
// (7) + t1.{B,A0} (5), vmcnt(5).
// =====================================================================
#define BK8 64
#define NT8 (EMB / BK8)  // 32
#define BN 192

#define LDA(dst, buf, half)                                                    \
  _Pragma("unroll")                                                            \
  for (int i_ = 0; i_ < 4; ++i_) {                                             \
    const int row_ = wm + (half) * 64 + i_ * 16 + l15;                         \
    _Pragma("unroll")                                                          \
    for (int ks_ = 0; ks_ < 2; ++ks_)                                          \
      dst[i_][ks_] = *(const bf16x8*)&(buf)[row_ * 64 +                        \
                                            (((ks_ * 4 + lq) ^ (row_ & 7)) * 8)]; \
  }

#define LDB2(dst, buf)                                                         \
  _Pragma("unroll")                                                            \
  for (int j_ = 0; j_ < 2; ++j_) {                                             \
    const int row_ = 256 + wn + j_ * 16 + l15;                                 \
    _Pragma("unroll")                                                          \
    for (int ks_ = 0; ks_ < 2; ++ks_)                                          \
      dst[j_][ks_] = *(const bf16x8*)&(buf)[row_ * 64 +                        \
                                            (((ks_ * 4 + lq) ^ (row_ & 7)) * 8)]; \
  }

#define LDB1(dst, buf)                                                         \
  {                                                                            \
    const int row_ = 256 + wn + 32 + l15;                                      \
    _Pragma("unroll")                                                          \
    for (int ks_ = 0; ks_ < 2; ++ks_)                                          \
      dst[ks_] = *(const bf16x8*)&(buf)[row_ * 64 +                            \
                                        (((ks_ * 4 + lq) ^ (row_ & 7)) * 8)];  \
  }

#define MM16(Af, Bf, ai)                                                       \
  __builtin_amdgcn_s_setprio(1);                                               \
  _Pragma("unroll")                                                            \
  for (int ks_ = 0; ks_ < 2; ++ks_)                                            \
    _Pragma("unroll")                                                          \
    for (int i_ = 0; i_ < 4; ++i_)                                             \
      _Pragma("unroll")                                                        \
      for (int j_ = 0; j_ < 2; ++j_)                                           \
        acc[(ai) + i_][j_] = __builtin_amdgcn_mfma_f32_16x16x32_bf16(          \
            Af[i_][ks_], Bf[j_][ks_], acc[(ai) + i_][j_], 0, 0, 0);            \
  __builtin_amdgcn_s_setprio(0);

#define MM8(Af, Bf, ai)                                                        \
  __builtin_amdgcn_s_setprio(1);                                               \
  _Pragma("unroll")                                                            \
  for (int ks_ = 0; ks_ < 2; ++ks_)                                            \
    _Pragma("unroll")                                                          \
    for (int i_ = 0; i_ < 4; ++i_)                                             \
      acc[(ai) + i_][2] = __builtin_amdgcn_mfma_f32_16x16x32_bf16(             \
          Af[i_][ks_], Bf[ks_], acc[(ai) + i_][2], 0, 0, 0);                   \
  __builtin_amdgcn_s_setprio(0);

__global__ __launch_bounds__(512, 2)
void gemm_qkv8(const bf16_t* __restrict__ A,
               const bf16_t* __restrict__ Wq, const bf16_t* __restrict__ Wk,
               const bf16_t* __restrict__ Wv,
               bf16_t* __restrict__ Qb, bf16_t* __restrict__ Kb,
               bf16_t* __restrict__ Vt, float qalpha)
{
  // rows 0..255: A tile; rows 256..447: B tile (192 rows). stride 64 elem.
  __shared__ bf16_t lds0[448 * 64];
  __shared__ bf16_t lds1[448 * 64];

  const int tid  = threadIdx.x;
  const int lane = tid & 63;
  const int wv   = tid >> 6;
  const int l15  = lane & 15;
  const int lq   = lane >> 4;

  // XCD-aware bijective swizzle: 256 blocks = 8 XCDs x 32.
  const int bid0 = blockIdx.x;
  const int bid  = (bid0 & 7) * 32 + (bid0 >> 3);
  const int mt = bid >> 4, nt = bid & 15;
  const int m0 = mt * 256;
  const int ncol0g = nt * BN;          // global output-column base (0..2880)

  const int wm = (wv >> 2) * 128;      // wave M offset (0/128)
  const int wn = (wv & 3) * 48;        // wave N offset (0/48/96/144)

  f32x4 acc[8][3] = {};

  // ---- staging (linear LDS dest + inverse-swizzled global source) ----
  auto stageA_half = [&](bf16_t* dstbuf, int tsrc, int half) {  // 2 loads
    const int k0 = tsrc * BK8;
#pragma unroll
    for (int r = 0; r < 2; ++r) {
      const int c = (half * 2 + r) * 512 + tid;   // granules 0..2047
      const int row = c >> 3, p = c & 7;
      const int sb = p ^ (row & 7);
      GL2LDS16(A + (size_t)(m0 + row) * EMB + k0 + sb * 8, dstbuf + c * 8);
    }
  };
  auto stageB = [&](bf16_t* dstbuf, int tsrc) {                 // 3 loads
    const int k0 = tsrc * BK8;
#pragma unroll
    for (int r = 0; r < 3; ++r) {
      const int c = r * 512 + tid;                // granules 0..1535
      const int row = c >> 3, p = c & 7;
      const int sb = p ^ (row & 7);
      const int gc = ncol0g + row;                // global out-col for row
      const bf16_t* bsrc; int brow;
      if (gc < EMB)             { bsrc = Wq; brow = gc; }
      else if (gc < EMB + 512)  { bsrc = Wk; brow = gc - EMB; }
      else                      { bsrc = Wv; brow = gc - EMB - 512; }
      GL2LDS16(bsrc + (size_t)brow * EMB + k0 + sb * 8,
               dstbuf + 256 * 64 + c * 8);
    }
  };

  // ---- prologue: t0 full (7) + t1.{B,A0} (5); vmcnt(5) -> t0 landed ----
  stageA_half(lds0, 0, 0); stageA_half(lds0, 0, 1); stageB(lds0, 0);
  stageB(lds1, 1); stageA_half(lds1, 1, 0);
  asm volatile("s_waitcnt vmcnt(5)" ::: "memory");
  __builtin_amdgcn_s_barrier();

  bf16x8 a03[4][2], a47[4][2], b01[2][2], b2[2];

#pragma unroll 1
  for (int t = 0; t < NT8; ++t) {
    bf16_t* curb = (t & 1) ? lds1 : lds0;
    bf16_t* nxtb = (t & 1) ? lds0 : lds1;
    const int tn1 = (t + 1 < NT8) ? t + 1 : NT8 - 1;  // clamp src only;
    const int tn2 = (t + 2 < NT8) ? t + 2 : NT8 - 1;  // dest parity fixed

    // -- ph1: read a03,b01(cur); stage (t+1).A1 -> nxt; MFMA(a03,b01) --
    LDA(a03, curb, 0);
    LDB2(b01, curb);
    stageA_half(nxtb, tn1, 1);
    __builtin_amdgcn_s_barrier();
    MM16(a03, b01, 0);
    __builtin_amdgcn_s_barrier();

    // -- ph2: read b2(cur); MFMA(a03,b2) --
    LDB1(b2, curb);
    __builtin_amdgcn_s_barrier();
    MM8(a03, b2, 0);
    __builtin_amdgcn_s_barrier();

    // -- ph3: read a47(cur); stage (t+2).B -> cur (B free after ph2);
    //         MFMA(a47,b2) --
    LDA(a47, curb, 1);
    stageB(curb, tn2);
    __builtin_amdgcn_s_barrier();
    MM8(a47, b2, 4);
    __builtin_amdgcn_s_barrier();

    // -- ph4: stage (t+2).A0 -> cur (A free after ph3); MFMA(a47,b01);
    //         vmcnt(5): retire ALL of t+1, keep (t+2).{B,A0} in flight --
    stageA_half(curb, tn2, 0);
    __builtin_amdgcn_s_barrier();
    MM16(a47, b01, 4);
    asm volatile("s_waitcnt vmcnt(5)" ::: "memory");
    __builtin_amdgcn_s_barrier();
  }
  asm volatile("s_waitcnt vmcnt(0)" ::: "memory");  // drain tail dummies

  // ---- epilogue: per-fragment destination select ----
  const int bb = m0 >> 11;
  const int mloc0 = (m0 & 2047) + wm + lq * 4;
#pragma unroll
  for (int i = 0; i < 8; ++i) {
    const int rbase = m0 + wm + i * 16 + lq * 4;
#pragma unroll
    for (int j = 0; j < 3; ++j) {
      const int gc0 = ncol0g + wn + j * 16;     // fragment col base (x16)
      if (gc0 < EMB) {              // Q: scale + row-major (4096,2048)
        const int col = gc0 + l15;
#pragma unroll
        for (int r = 0; r < 4; ++r)
          Qb[(size_t)(rbase + r) * EMB + col] = (bf16_t)(acc[i][j][r] * qalpha);
      } else if (gc0 < EMB + 512) { // K: row-major (4096,512)
        const int col = gc0 - EMB + l15;
#pragma unroll
        for (int r = 0; r < 4; ++r)
          Kb[(size_t)(rbase + r) * KVDIM + col] = (bf16_t)acc[i][j][r];
      } else {                      // V: transposed, 4 consecutive t/lane
        const int d = gc0 - EMB - 512 + l15;
        const int mloc = mloc0 + i * 16;
        *(bf16x4*)(Vt + (size_t)(bb * KVDIM + d) * T_SEQ + mloc) =
            bf16x4{(__bf16)acc[i][j][0], (__bf16)acc[i][j][1],
                   (__bf16)acc[i][j][2], (__bf16)acc[i][j][3]};
      }
    }
  }
}

// =====================================================================
// GEMM (out-projection): fp32 out.
// =====================================================================
__global__ __launch_bounds__(256, 2)
void gemm_out(const bf16_t* __restrict__ A, const bf16_t* __restrict__ Bm,
              float* __restrict__ C, int M, int N, int K)
{
  __shared__ bf16_t As[128 * 64];
  __shared__ bf16_t Bs[128 * 64];

  const int tid  = threadIdx.x;
  const int lane = tid & 63;
  const int wv   = tid >> 6;
  const int m0 = blockIdx.y * 128;
  const int n0 = blockIdx.x * 128;
  const int wm = (wv >> 1) * 64;
  const int wn = (wv & 1) * 64;
  const int l15 = lane & 15;
  const int lq  = lane >> 4;

  f32x4 acc[4][4] = {};
  const int srow = tid >> 3;
  const int scol = (tid & 7) * 8;

  for (int k0 = 0; k0 < K; k0 += 64) {
#pragma unroll
    for (int r = 0; r < 4; ++r) {
      const int row = r * 32 + srow;
      GL2LDS16(A + (size_t)(m0 + row) * K + k0 + scol, As + row * 64 + scol);
    }
#pragma unroll
    for (int r = 0; r < 4; ++r) {
      const int row = r * 32 + srow;
      GL2LDS16(Bm + (size_t)(n0 + row) * K + k0 + scol, Bs + row * 64 + scol);
    }
    __syncthreads();

#pragma unroll
    for (int ks = 0; ks < 2; ++ks) {
      const int kc = ks * 32 + lq * 8;
      bf16x8 af[4], bf[4];
#pragma unroll
      for (int i = 0; i < 4; ++i)
        af[i] = *(const bf16x8*)(As + (wm + i * 16 + l15) * 64 + kc);
#pragma unroll
      for (int j = 0; j < 4; ++j)
        bf[j] = *(const bf16x8*)(Bs + (wn + j * 16 + l15) * 64 + kc);
#pragma unroll
      for (int i = 0; i < 4; ++i)
#pragma unroll
        for (int j = 0; j < 4; ++j)
          acc[i][j] = __builtin_amdgcn_mfma_f32_16x16x32_bf16(af[i], bf[j], acc[i][j], 0, 0, 0);
    }
    __syncthreads();
  }

#pragma unroll
  for (int i = 0; i < 4; ++i) {
    const int rbase = m0 + wm + i * 16 + lq * 4;
#pragma unroll
    for (int j = 0; j < 4; ++j) {
      const int col = n0 + wn + j * 16 + l15;
#pragma unroll
      for (int r = 0; r < 4; ++r)
        C[(size_t)(rbase + r) * N + col] = acc[i][j][r];
    }
  }
}

// =====================================================================
// Flash attention. Causal, GQA, no-max exp2 softmax, S^T orientation,
// P via per-wave LDS, x32 PV. q-tile 64 (16 rows/wave); kv tile 64;
// K/V double-buffered. Grid (16,NH,B): block x does qt=31-x then qt=x.
// =====================================================================
#define PSTR 72   // row stride (elements); 144 B = 16B-aligned

__global__ __launch_bounds__(256, 2)
void attn_fwd(const bf16_t* __restrict__ Q, const bf16_t* __restrict__ Kg,
              const bf16_t* __restrict__ Vt, bf16_t* __restrict__ Y)
{
  __shared__ bf16_t Ks[2][64 * 128];   // [t 0..63][16B blk], blk = pos ^ (t&7)
  __shared__ bf16_t Vs[2][128 * 64];   // [d 0..127][16B blk], blk = pos ^ (d&7)
  __shared__ bf16_t Ps[4][16 * PSTR];  // per-wave P[q 0..15][kv 0..63]

  const int tid  = threadIdx.x;
  const int lane = tid & 63;
  const int wv   = tid >> 6;
  const int l15  = lane & 15;
  const int lq   = lane >> 4;
  const int h  = blockIdx.y;
  const int b  = blockIdx.z;
  const int hkv = h >> 2;
  bf16_t* Psw = Ps[wv];

  auto stage = [&](int kt, int bufsel) {
    const int base_t = b * T_SEQ + kt * 64;
#pragma unroll
    for (int r = 0; r < 4; ++r) {
      const int c = r * 256 + tid;
      const int row = c >> 4, p = c & 15;
      const int sb = p ^ (row & 7);
      GL2LDS16(Kg + (size_t)(base_t + row) * KVDIM + hkv * HD + sb * 8,
               &Ks[bufsel][c * 8]);
    }
#pragma unroll
    for (int r = 0; r < 4; ++r) {
      const int c = r * 256 + tid;
      const int row = c >> 3, p = c & 7;
      const int sb = p ^ (row & 7);
      GL2LDS16(Vt + (size_t)(b * KVDIM + hkv * HD + row) * T_SEQ + kt * 64 + sb * 8,
               &Vs[bufsel][c * 8]);
    }
  };

#pragma unroll 1
  for (int ph = 0; ph < 2; ++ph) {
    const int qt = ph ? blockIdx.x : (31 - blockIdx.x);
    const int q0 = qt * 64;
    const int nkt = qt + 1;
    const int qabs = q0 + wv * 16 + l15;   // this lane's q row

    // Q fragments (B-operand: n=l15=q, k=lq*8+j). Q pre-scaled.
    bf16x8 qf[4];
    {
      const bf16_t* qp = Q + ((size_t)(b * T_SEQ + qabs) * NH + h) * HD + lq * 8;
#pragma unroll
      for (int ds = 0; ds < 4; ++ds)
        qf[ds] = *(const bf16x8*)(qp + ds * 32);
    }

    float l_part = 0.f;
    f32x4 o[8];
#pragma unroll
    for (int nb = 0; nb < 8; ++nb) o[nb] = f32x4{0.f, 0.f, 0.f, 0.f};

    __syncthreads();            // prior phase done reading buffers
    stage(0, 0);

    for (int kt = 0; kt < nkt; ++kt) {
      const int cur = kt & 1;
      __syncthreads();          // stage(kt) complete
      if (kt + 1 < nkt) stage(kt + 1, cur ^ 1);

      // ---- S^T = K Q^T : D[kv][q], lane: q=l15, kv=nb*16+lq*4+r ----
      f32x4 s[4];
#pragma unroll
      for (int nb = 0; nb < 4; ++nb) {
        s[nb] = f32x4{0.f, 0.f, 0.f, 0.f};
        const int row = nb * 16 + l15;
        const int r7  = row & 7;
#pragma unroll
        for (int ds = 0; ds < 4; ++ds) {
          const bf16x8 kf = *(const bf16x8*)&Ks[cur][row * 128 + (((ds * 4 + lq) ^ r7) * 8)];
          s[nb] = __builtin_amdgcn_mfma_f32_16x16x32_bf16(kf, qf[ds], s[nb], 0, 0, 0);
        }
      }

      // ---- p = exp2(s) raw (no max), mask only on diagonal tile ----
      const bool dia = (kt == nkt - 1);
#pragma unroll
      for (int nb = 0; nb < 4; ++nb) {
        const int kvb = kt * 64 + nb * 16 + lq * 4;
        float p0, p1, p2, p3;
        if (dia) {
          p0 = (kvb + 0 <= qabs) ? fast_exp2(s[nb][0]) : 0.f;
          p1 = (kvb + 1 <= qabs) ? fast_exp2(s[nb][1]) : 0.f;
          p2 = (kvb + 2 <= qabs) ? fast_exp2(s[nb][2]) : 0.f;
          p3 = (kvb + 3 <= qabs) ? fast_exp2(s[nb][3]) : 0.f;
        } else {
          p0 = fast_exp2(s[nb][0]);
          p1 = fast_exp2(s[nb][1]);
          p2 = fast_exp2(s[nb][2]);
          p3 = fast_exp2(s[nb][3]);
        }
        l_part += (p0 + p1) + (p2 + p3);
        *(bf16x4*)(Psw + l15 * PSTR + nb * 16 + lq * 4) =
            bf16x4{(__bf16)p0, (__bf16)p1, (__bf16)p2, (__bf16)p3};
      }

      // wait ONLY LDS (keep K/V prefetch in flight)
      asm volatile("s_waitcnt lgkmcnt(0)" ::: "memory");

      // ---- O^T += V^T P^T : D[d][q], lane: q=l15, d=nb*16+lq*4+r ----
#pragma unroll
      for (int ks = 0; ks < 2; ++ks) {
        const bf16x8 pf = *(const bf16x8*)(Psw + l15 * PSTR + ks * 32 + lq * 8);
#pragma unroll
        for (int nb = 0; nb < 8; ++nb) {
          const int row = nb * 16 + l15;
          const bf16x8 vf = *(const bf16x8*)&Vs[cur][row * 64 + (((ks * 4 + lq) ^ (row & 7)) * 8)];
          o[nb] = __builtin_amdgcn_mfma_f32_16x16x32_bf16(vf, pf, o[nb], 0, 0, 0);
        }
      }
    }

    // ---- epilogue: reduce l over lq-group (lanes l15+16*lq), store ----
    float lt = l_part;
    lt += __shfl_xor(lt, 16);
    lt += __shfl_xor(lt, 32);
    const float inv = 1.f / lt;
    bf16_t* yp = Y + ((size_t)(b * T_SEQ + qabs) * NH + h) * HD + lq * 4;
#pragma unroll
    for (int nb = 0; nb < 8; ++nb) {
      *(bf16x4*)(yp + nb * 16) = bf16x4{(__bf16)(o[nb][0] * inv), (__bf16)(o[nb][1] * inv),
                                        (__bf16)(o[nb][2] * inv), (__bf16)(o[nb][3] * inv)};
    }
  }
}

// =====================================================================
// launch
// =====================================================================
extern "C" void kernel_launch(void* const* d_in, const int* in_sizes, int n_in,
                              void* d_out, int out_size, void* d_ws, size_t ws_size,
                              hipStream_t stream) {
  const float* x  = (const float*)d_in[0];
  const float* wq = (const float*)d_in[1];
  const float* wk = (const float*)d_in[2];
  const float* wv = (const float*)d_in[3];
  const float* wo = (const float*)d_in[4];
  float* out = (float*)d_out;

  const size_t n_x  = (size_t)MROWS * EMB;
  const size_t n_wq = (size_t)EMB * EMB;
  const size_t n_wk = (size_t)KVDIM * EMB;

  bf16_t* xb  = (bf16_t*)d_ws;
  bf16_t* wqb = xb  + n_x;
  bf16_t* wkb = wqb + n_wq;
  bf16_t* wvb = wkb + n_wk;
  bf16_t* wob = wvb + n_wk;
  bf16_t* Qb  = wob + n_wq;                  // 4096*2048
  bf16_t* Kb  = Qb + (size_t)MROWS * EMB;    // 4096*512
  bf16_t* Vtb = Kb + (size_t)MROWS * KVDIM;  // (B*512)*2048 transposed V
  bf16_t* Yb  = Vtb + (size_t)MROWS * KVDIM; // 4096*2048

  dim3 blk(256);

  cvt_all<<<dim3(18432), blk, 0, stream>>>(
      (const float4*)x, (const float4*)wq, (const float4*)wk, (const float4*)wv, (const float4*)wo,
      (bf16x4*)xb, (bf16x4*)wqb, (bf16x4*)wkb, (bf16x4*)wvb, (bf16x4*)wob);

  const float qalpha = 0.08838834764831845f * 1.4426950408889634f;
  gemm_qkv8<<<dim3(256), dim3(512), 0, stream>>>(xb, wqb, wkb, wvb,
                                                 Qb, Kb, Vtb, qalpha);

  attn_fwd<<<dim3(16, NH, BATCH), blk, 0, stream>>>(Qb, Kb, Vtb, Yb);

  gemm_out<<<dim3(EMB / 128, MROWS / 128), blk, 0, stream>>>(Yb, wob, out, MROWS, EMB, EMB);
}